// Round 2
// baseline (11717.619 us; speedup 1.0000x reference)
//
#include <hip/hip_runtime.h>
#include <hip/hip_bf16.h>
#include <hip/hip_fp16.h>

// SVD-RNN: W = U diag(s) V from Householder chains; h_t = tanh(xp_t + W h_{t-1});
// out_t = h_t W_out^T + b_out.
#define BB 64
#define TT 2048
#define II 128
#define HH 256
#define OO 128

typedef _Float16 f16x2 __attribute__((ext_vector_type(2)));

#if __has_builtin(__builtin_amdgcn_fdot2)
__device__ __forceinline__ float fdot2(f16x2 a, f16x2 b, float c) {
    return __builtin_amdgcn_fdot2(a, b, c, false);
}
#else
__device__ __forceinline__ float fdot2(f16x2 a, f16x2 b, float c) {
    return fmaf((float)a.x, (float)b.x, fmaf((float)a.y, (float)b.y, c));
}
#endif

__device__ __forceinline__ float tanh_fast(float x) {
    float xc = fminf(fmaxf(x, -9.0f), 9.0f);
    float e = __expf(2.0f * xc);
    return (e - 1.0f) * __fdividef(1.0f, e + 1.0f);
}

// ---------------------------------------------------------------------------
// Kernel 1: masked+flipped Householder vectors and betas.
// ---------------------------------------------------------------------------
__global__ __launch_bounds__(64) void prep_kernel(
    const float* __restrict__ u_raw, const float* __restrict__ v_raw,
    float* __restrict__ u_eff, float* __restrict__ v_eff,
    float* __restrict__ beta_u, float* __restrict__ beta_v)
{
    const int row = blockIdx.x;
    const int lane = threadIdx.x;
    const bool isU = row < HH;
    const int i = isU ? row : row - HH;
    const float* src = isU ? (u_raw + (size_t)i * HH) : (v_raw + (size_t)(HH - 1 - i) * HH);
    float* dst = (isU ? u_eff : v_eff) + (size_t)i * HH;
    const int lo = isU ? (HH - 1 - i) : i;
    float ss = 0.0f;
    for (int c = lane; c < HH; c += 64) {
        float vv = (c >= lo) ? src[HH - 1 - c] : 0.0f;
        dst[c] = vv;
        ss += vv * vv;
    }
    for (int m = 1; m < 64; m <<= 1) ss += __shfl_xor(ss, m, 64);
    if (lane == 0) (isU ? beta_u : beta_v)[i] = 2.0f / ss;
}

// ---------------------------------------------------------------------------
// Kernel 2: Householder chain per column.
// ---------------------------------------------------------------------------
__global__ __launch_bounds__(256) void hh_kernel(
    const float* __restrict__ u_eff, const float* __restrict__ v_eff,
    const float* __restrict__ beta_u, const float* __restrict__ beta_v,
    float* __restrict__ Ucol, float* __restrict__ Vrow)
{
    const int wid = blockIdx.x * 4 + (threadIdx.x >> 6);
    const int lane = threadIdx.x & 63;
    const bool isU = wid < HH;
    const int j = isU ? wid : wid - HH;
    const float* eff = isU ? u_eff : v_eff;
    const float* beta = isU ? beta_u : beta_v;

    float cr0 = (j == 4 * lane + 0) ? 1.0f : 0.0f;
    float cr1 = (j == 4 * lane + 1) ? 1.0f : 0.0f;
    float cr2 = (j == 4 * lane + 2) ? 1.0f : 0.0f;
    float cr3 = (j == 4 * lane + 3) ? 1.0f : 0.0f;

    const int i0 = isU ? (HH - 1 - j) : 0;
    for (int i = i0; i < HH; ++i) {
        const float4 v4 = *(const float4*)(eff + (size_t)i * HH + lane * 4);
        float d = v4.x * cr0 + v4.y * cr1 + v4.z * cr2 + v4.w * cr3;
        for (int m = 1; m < 64; m <<= 1) d += __shfl_xor(d, m, 64);
        const float t = beta[i] * d;
        cr0 = fmaf(-t, v4.x, cr0);
        cr1 = fmaf(-t, v4.y, cr1);
        cr2 = fmaf(-t, v4.z, cr2);
        cr3 = fmaf(-t, v4.w, cr3);
    }
    if (isU) {
        *(float4*)(Ucol + (size_t)j * HH + lane * 4) = make_float4(cr0, cr1, cr2, cr3);
    } else {
        Vrow[(size_t)(4 * lane + 0) * HH + j] = cr0;
        Vrow[(size_t)(4 * lane + 1) * HH + j] = cr1;
        Vrow[(size_t)(4 * lane + 2) * HH + j] = cr2;
        Vrow[(size_t)(4 * lane + 3) * HH + j] = cr3;
    }
}

// ---------------------------------------------------------------------------
// Kernel 3: W[r][c] = sum_k Ucol[k][r] * sig[k] * Vrow[k][c]
// ---------------------------------------------------------------------------
__global__ __launch_bounds__(256) void w_kernel(
    const float* __restrict__ Ucol, const float* __restrict__ Vrow,
    const float* __restrict__ sig, float* __restrict__ Wm)
{
    const int r = blockIdx.x;
    const int c = threadIdx.x;
    float acc = 0.0f;
    #pragma unroll 4
    for (int k = 0; k < HH; ++k) {
        acc = fmaf(Ucol[(size_t)k * HH + r] * sig[k], Vrow[(size_t)k * HH + c], acc);
    }
    Wm[(size_t)r * HH + c] = acc;
}

// ---------------------------------------------------------------------------
// Tiled GEMM with bias: C[M][N] = A[M][K] * B[N][K]^T + bias[N]
// ---------------------------------------------------------------------------
__device__ __forceinline__ void load8f(float* dst, const float* p) {
    float4 a = *(const float4*)p;
    float4 b = *(const float4*)(p + 4);
    dst[0] = a.x; dst[1] = a.y; dst[2] = a.z; dst[3] = a.w;
    dst[4] = b.x; dst[5] = b.y; dst[6] = b.z; dst[7] = b.w;
}
__device__ __forceinline__ void load8f(float* dst, const __half* p) {
    uint4 u = *(const uint4*)p;
    f16x2 h0 = __builtin_bit_cast(f16x2, u.x);
    f16x2 h1 = __builtin_bit_cast(f16x2, u.y);
    f16x2 h2 = __builtin_bit_cast(f16x2, u.z);
    f16x2 h3 = __builtin_bit_cast(f16x2, u.w);
    dst[0] = (float)h0.x; dst[1] = (float)h0.y;
    dst[2] = (float)h1.x; dst[3] = (float)h1.y;
    dst[4] = (float)h2.x; dst[5] = (float)h2.y;
    dst[6] = (float)h3.x; dst[7] = (float)h3.y;
}
__device__ __forceinline__ void storeC(float* p, float v) { *p = v; }
__device__ __forceinline__ void storeC(__half* p, float v) { *p = __float2half_rn(v); }

template <typename AT, typename OT>
__global__ __launch_bounds__(256) void gemm_bias(
    const AT* __restrict__ A, const float* __restrict__ Bm,
    const float* __restrict__ bias, OT* __restrict__ C,
    int M, int N, int K)
{
    __shared__ float As[64][36];
    __shared__ float Bs[64][36];
    const int m0 = blockIdx.x * 64;
    const int n0 = blockIdx.y * 64;
    const int tid = threadIdx.x;
    const int lr = tid >> 2;
    const int lc = (tid & 3) << 3;
    const int tm = tid >> 4;
    const int tn = tid & 15;
    float acc[4][4] = {};
    for (int k0 = 0; k0 < K; k0 += 32) {
        load8f(&As[lr][lc], A + (size_t)(m0 + lr) * K + k0 + lc);
        load8f(&Bs[lr][lc], Bm + (size_t)(n0 + lr) * K + k0 + lc);
        __syncthreads();
        #pragma unroll
        for (int k4 = 0; k4 < 32; k4 += 4) {
            float4 a4[4], b4[4];
            #pragma unroll
            for (int r = 0; r < 4; ++r) {
                a4[r] = *(const float4*)&As[tm * 4 + r][k4];
                b4[r] = *(const float4*)&Bs[tn + 16 * r][k4];
            }
            #pragma unroll
            for (int i2 = 0; i2 < 4; ++i2) {
                #pragma unroll
                for (int j2 = 0; j2 < 4; ++j2) {
                    acc[i2][j2] = fmaf(a4[i2].x, b4[j2].x, acc[i2][j2]);
                    acc[i2][j2] = fmaf(a4[i2].y, b4[j2].y, acc[i2][j2]);
                    acc[i2][j2] = fmaf(a4[i2].z, b4[j2].z, acc[i2][j2]);
                    acc[i2][j2] = fmaf(a4[i2].w, b4[j2].w, acc[i2][j2]);
                }
            }
        }
        __syncthreads();
    }
    #pragma unroll
    for (int j2 = 0; j2 < 4; ++j2) {
        const int n = n0 + tn + 16 * j2;
        const float bv = bias[n];
        #pragma unroll
        for (int i2 = 0; i2 < 4; ++i2) {
            const int m = m0 + tm * 4 + i2;
            storeC(C + (size_t)m * N + n, acc[i2][j2] + bv);
        }
    }
}

// ---------------------------------------------------------------------------
// Kernel 5: recurrence. 64 WGs (1/batch) x 1024 threads (16 waves).
// Wave q owns k-slice [q*16, q*16+16); lane l owns rows j = {l, l+64, l+128,
// l+192}. W fragment in registers as f16 pairs (v_dot2_f32_f16, f32 accum).
// Per step: 2 uniform b128 LDS reads of the h slice -> 32 dot2 -> 4
// ds_add_f32 (consecutive per-lane addresses, conflict-free) into acc[p];
// barrier; 128 threads: b64 read + re-zero acc, tanh, packed half2 write to
// hbuf + global; barrier. xp prefetched one step ahead.
// ---------------------------------------------------------------------------
__global__ __launch_bounds__(1024, 1) void recur_kernel(
    const float* __restrict__ Wm,              // [256][256] f32 row-major
    const __half* __restrict__ xp,             // [B][T][256] f16
    __half* __restrict__ hall)                 // [B][T][256] f16
{
    const int b = blockIdx.x;
    const int tid = threadIdx.x;
    const int l = tid & 63;
    const int q = tid >> 6;

    __shared__ float acc[2][HH];
    __shared__ unsigned int hbits[2][HH / 2];  // h as packed f16x2

    // Load W fragment: rows j = l + 64r, cols q*16..q*16+16, converted to f16.
    f16x2 w2[4][8];
    #pragma unroll
    for (int r = 0; r < 4; ++r) {
        const float* Wp = Wm + (size_t)(l + 64 * r) * HH + q * 16;
        #pragma unroll
        for (int c4 = 0; c4 < 4; ++c4) {
            float4 f = *(const float4*)(Wp + c4 * 4);
            w2[r][c4 * 2 + 0] = f16x2{(_Float16)f.x, (_Float16)f.y};
            w2[r][c4 * 2 + 1] = f16x2{(_Float16)f.z, (_Float16)f.w};
        }
    }
    if (tid < HH) { acc[0][tid] = 0.0f; acc[1][tid] = 0.0f; }
    if (tid < HH / 2) hbits[0][tid] = 0u;
    __syncthreads();

    const unsigned int* xpw = (const unsigned int*)(xp + (size_t)b * TT * HH);
    unsigned int* hw = (unsigned int*)(hall + (size_t)b * TT * HH);
    unsigned int xpc = (tid < 128) ? xpw[tid] : 0u;

    for (int t = 0; t < TT; ++t) {
        const int p = t & 1;
        // wave-uniform broadcast read of this wave's 16-element h slice (32 B)
        uint4 ha = *(const uint4*)&hbits[p][q * 8];
        uint4 hb4 = *(const uint4*)&hbits[p][q * 8 + 4];
        f16x2 hv[8] = {
            __builtin_bit_cast(f16x2, ha.x),  __builtin_bit_cast(f16x2, ha.y),
            __builtin_bit_cast(f16x2, ha.z),  __builtin_bit_cast(f16x2, ha.w),
            __builtin_bit_cast(f16x2, hb4.x), __builtin_bit_cast(f16x2, hb4.y),
            __builtin_bit_cast(f16x2, hb4.z), __builtin_bit_cast(f16x2, hb4.w)};
        float a0 = 0.f, a1 = 0.f, a2 = 0.f, a3 = 0.f;
        #pragma unroll
        for (int c = 0; c < 8; ++c) {
            a0 = fdot2(w2[0][c], hv[c], a0);
            a1 = fdot2(w2[1][c], hv[c], a1);
            a2 = fdot2(w2[2][c], hv[c], a2);
            a3 = fdot2(w2[3][c], hv[c], a3);
        }
        atomicAdd(&acc[p][l], a0);
        atomicAdd(&acc[p][l + 64], a1);
        atomicAdd(&acc[p][l + 128], a2);
        atomicAdd(&acc[p][l + 192], a3);

        unsigned int xpn = 0u;
        if (tid < 128 && t + 1 < TT) xpn = xpw[(size_t)(t + 1) * 128 + tid];
        __syncthreads();

        if (tid < 128) {
            float2 s2 = *(float2*)&acc[p][2 * tid];
            *(float2*)&acc[p][2 * tid] = make_float2(0.0f, 0.0f);  // re-zero for t+2
            f16x2 xv = __builtin_bit_cast(f16x2, xpc);
            float h0 = tanh_fast(s2.x + (float)xv.x);
            float h1 = tanh_fast(s2.y + (float)xv.y);
            unsigned int hb2 = __builtin_bit_cast(unsigned int,
                                                  f16x2{(_Float16)h0, (_Float16)h1});
            hbits[p ^ 1][tid] = hb2;
            hw[(size_t)t * 128 + tid] = hb2;
            xpc = xpn;
        }
        __syncthreads();
    }
}

// ---------------------------------------------------------------------------
extern "C" void kernel_launch(void* const* d_in, const int* in_sizes, int n_in,
                              void* d_out, int out_size, void* d_ws, size_t ws_size,
                              hipStream_t stream) {
    const float* x     = (const float*)d_in[0];   // [B][T][I]
    const float* W_in  = (const float*)d_in[1];   // [H][I]
    const float* b_in  = (const float*)d_in[2];   // [H]
    const float* W_out = (const float*)d_in[3];   // [O][H]
    const float* b_out = (const float*)d_in[4];   // [O]
    const float* u_raw = (const float*)d_in[5];   // [M][H]
    const float* sig   = (const float*)d_in[6];   // [H]
    const float* v_raw = (const float*)d_in[7];   // [M][H]
    float* out = (float*)d_out;                   // [B][T][O]

    char* ws = (char*)d_ws;
    size_t off = 0;
    auto alloc = [&](size_t bytes) -> void* {
        void* p = (void*)(ws + off);
        off += (bytes + 255) & ~((size_t)255);
        return p;
    };
    float* u_eff  = (float*)alloc((size_t)HH * HH * 4);
    float* v_eff  = (float*)alloc((size_t)HH * HH * 4);
    float* beta_u = (float*)alloc((size_t)HH * 4);
    float* beta_v = (float*)alloc((size_t)HH * 4);
    float* Ucol   = (float*)alloc((size_t)HH * HH * 4);
    float* Vrow   = (float*)alloc((size_t)HH * HH * 4);
    float* Wm     = (float*)alloc((size_t)HH * HH * 4);
    __half* xpbuf = (__half*)alloc((size_t)BB * TT * HH * 2);
    __half* hall  = (__half*)alloc((size_t)BB * TT * HH * 2);
    (void)ws_size; (void)in_sizes; (void)n_in; (void)out_size;

    prep_kernel<<<2 * HH, 64, 0, stream>>>(u_raw, v_raw, u_eff, v_eff, beta_u, beta_v);
    hh_kernel<<<(2 * HH) / 4, 256, 0, stream>>>(u_eff, v_eff, beta_u, beta_v, Ucol, Vrow);
    w_kernel<<<HH, HH, 0, stream>>>(Ucol, Vrow, sig, Wm);
    gemm_bias<float, __half>
        <<<dim3((BB * TT) / 64, HH / 64), 256, 0, stream>>>(x, W_in, b_in, xpbuf, BB * TT, HH, II);
    recur_kernel<<<BB, 1024, 0, stream>>>(Wm, xpbuf, hall);
    gemm_bias<__half, float>
        <<<dim3((BB * TT) / 64, OO / 64), 256, 0, stream>>>(hall, W_out, b_out, out, BB * TT, OO, HH);
}

// Round 3
// 1728.494 us; speedup vs baseline: 6.7791x; 6.7791x over previous
//
#include <hip/hip_runtime.h>
#include <hip/hip_bf16.h>
#include <hip/hip_fp16.h>

// SVD-RNN: W = U diag(s) V from Householder chains; h_t = tanh(xp_t + W h_{t-1});
// out_t = h_t W_out^T + b_out.
#define BB 64
#define TT 2048
#define II 128
#define HH 256
#define OO 128

typedef _Float16 f16x2 __attribute__((ext_vector_type(2)));

#if __has_builtin(__builtin_amdgcn_fdot2)
__device__ __forceinline__ float fdot2(f16x2 a, f16x2 b, float c) {
    return __builtin_amdgcn_fdot2(a, b, c, false);
}
#else
__device__ __forceinline__ float fdot2(f16x2 a, f16x2 b, float c) {
    return fmaf((float)a.x, (float)b.x, fmaf((float)a.y, (float)b.y, c));
}
#endif

__device__ __forceinline__ float tanh_fast(float x) {
    float xc = fminf(fmaxf(x, -9.0f), 9.0f);
    float e = __expf(2.0f * xc);
    return (e - 1.0f) * __fdividef(1.0f, e + 1.0f);
}

// ---------------------------------------------------------------------------
// Kernel 1: masked+flipped Householder vectors and betas.
// ---------------------------------------------------------------------------
__global__ __launch_bounds__(64) void prep_kernel(
    const float* __restrict__ u_raw, const float* __restrict__ v_raw,
    float* __restrict__ u_eff, float* __restrict__ v_eff,
    float* __restrict__ beta_u, float* __restrict__ beta_v)
{
    const int row = blockIdx.x;
    const int lane = threadIdx.x;
    const bool isU = row < HH;
    const int i = isU ? row : row - HH;
    const float* src = isU ? (u_raw + (size_t)i * HH) : (v_raw + (size_t)(HH - 1 - i) * HH);
    float* dst = (isU ? u_eff : v_eff) + (size_t)i * HH;
    const int lo = isU ? (HH - 1 - i) : i;
    float ss = 0.0f;
    for (int c = lane; c < HH; c += 64) {
        float vv = (c >= lo) ? src[HH - 1 - c] : 0.0f;
        dst[c] = vv;
        ss += vv * vv;
    }
    for (int m = 1; m < 64; m <<= 1) ss += __shfl_xor(ss, m, 64);
    if (lane == 0) (isU ? beta_u : beta_v)[i] = 2.0f / ss;
}

// ---------------------------------------------------------------------------
// Kernel 2: Householder chain per column.
// ---------------------------------------------------------------------------
__global__ __launch_bounds__(256) void hh_kernel(
    const float* __restrict__ u_eff, const float* __restrict__ v_eff,
    const float* __restrict__ beta_u, const float* __restrict__ beta_v,
    float* __restrict__ Ucol, float* __restrict__ Vrow)
{
    const int wid = blockIdx.x * 4 + (threadIdx.x >> 6);
    const int lane = threadIdx.x & 63;
    const bool isU = wid < HH;
    const int j = isU ? wid : wid - HH;
    const float* eff = isU ? u_eff : v_eff;
    const float* beta = isU ? beta_u : beta_v;

    float cr0 = (j == 4 * lane + 0) ? 1.0f : 0.0f;
    float cr1 = (j == 4 * lane + 1) ? 1.0f : 0.0f;
    float cr2 = (j == 4 * lane + 2) ? 1.0f : 0.0f;
    float cr3 = (j == 4 * lane + 3) ? 1.0f : 0.0f;

    const int i0 = isU ? (HH - 1 - j) : 0;
    for (int i = i0; i < HH; ++i) {
        const float4 v4 = *(const float4*)(eff + (size_t)i * HH + lane * 4);
        float d = v4.x * cr0 + v4.y * cr1 + v4.z * cr2 + v4.w * cr3;
        for (int m = 1; m < 64; m <<= 1) d += __shfl_xor(d, m, 64);
        const float t = beta[i] * d;
        cr0 = fmaf(-t, v4.x, cr0);
        cr1 = fmaf(-t, v4.y, cr1);
        cr2 = fmaf(-t, v4.z, cr2);
        cr3 = fmaf(-t, v4.w, cr3);
    }
    if (isU) {
        *(float4*)(Ucol + (size_t)j * HH + lane * 4) = make_float4(cr0, cr1, cr2, cr3);
    } else {
        Vrow[(size_t)(4 * lane + 0) * HH + j] = cr0;
        Vrow[(size_t)(4 * lane + 1) * HH + j] = cr1;
        Vrow[(size_t)(4 * lane + 2) * HH + j] = cr2;
        Vrow[(size_t)(4 * lane + 3) * HH + j] = cr3;
    }
}

// ---------------------------------------------------------------------------
// Kernel 3: W[r][c] = sum_k Ucol[k][r] * sig[k] * Vrow[k][c]
// ---------------------------------------------------------------------------
__global__ __launch_bounds__(256) void w_kernel(
    const float* __restrict__ Ucol, const float* __restrict__ Vrow,
    const float* __restrict__ sig, float* __restrict__ Wm)
{
    const int r = blockIdx.x;
    const int c = threadIdx.x;
    float acc = 0.0f;
    #pragma unroll 4
    for (int k = 0; k < HH; ++k) {
        acc = fmaf(Ucol[(size_t)k * HH + r] * sig[k], Vrow[(size_t)k * HH + c], acc);
    }
    Wm[(size_t)r * HH + c] = acc;
}

// ---------------------------------------------------------------------------
// Tiled GEMM with bias: C[M][N] = A[M][K] * B[N][K]^T + bias[N]
// ---------------------------------------------------------------------------
__device__ __forceinline__ void load8f(float* dst, const float* p) {
    float4 a = *(const float4*)p;
    float4 b = *(const float4*)(p + 4);
    dst[0] = a.x; dst[1] = a.y; dst[2] = a.z; dst[3] = a.w;
    dst[4] = b.x; dst[5] = b.y; dst[6] = b.z; dst[7] = b.w;
}
__device__ __forceinline__ void load8f(float* dst, const __half* p) {
    uint4 u = *(const uint4*)p;
    f16x2 h0 = __builtin_bit_cast(f16x2, u.x);
    f16x2 h1 = __builtin_bit_cast(f16x2, u.y);
    f16x2 h2 = __builtin_bit_cast(f16x2, u.z);
    f16x2 h3 = __builtin_bit_cast(f16x2, u.w);
    dst[0] = (float)h0.x; dst[1] = (float)h0.y;
    dst[2] = (float)h1.x; dst[3] = (float)h1.y;
    dst[4] = (float)h2.x; dst[5] = (float)h2.y;
    dst[6] = (float)h3.x; dst[7] = (float)h3.y;
}
__device__ __forceinline__ void storeC(float* p, float v) { *p = v; }
__device__ __forceinline__ void storeC(__half* p, float v) { *p = __float2half_rn(v); }

template <typename AT, typename OT>
__global__ __launch_bounds__(256) void gemm_bias(
    const AT* __restrict__ A, const float* __restrict__ Bm,
    const float* __restrict__ bias, OT* __restrict__ C,
    int M, int N, int K)
{
    __shared__ float As[64][36];
    __shared__ float Bs[64][36];
    const int m0 = blockIdx.x * 64;
    const int n0 = blockIdx.y * 64;
    const int tid = threadIdx.x;
    const int lr = tid >> 2;
    const int lc = (tid & 3) << 3;
    const int tm = tid >> 4;
    const int tn = tid & 15;
    float acc[4][4] = {};
    for (int k0 = 0; k0 < K; k0 += 32) {
        load8f(&As[lr][lc], A + (size_t)(m0 + lr) * K + k0 + lc);
        load8f(&Bs[lr][lc], Bm + (size_t)(n0 + lr) * K + k0 + lc);
        __syncthreads();
        #pragma unroll
        for (int k4 = 0; k4 < 32; k4 += 4) {
            float4 a4[4], b4[4];
            #pragma unroll
            for (int r = 0; r < 4; ++r) {
                a4[r] = *(const float4*)&As[tm * 4 + r][k4];
                b4[r] = *(const float4*)&Bs[tn + 16 * r][k4];
            }
            #pragma unroll
            for (int i2 = 0; i2 < 4; ++i2) {
                #pragma unroll
                for (int j2 = 0; j2 < 4; ++j2) {
                    acc[i2][j2] = fmaf(a4[i2].x, b4[j2].x, acc[i2][j2]);
                    acc[i2][j2] = fmaf(a4[i2].y, b4[j2].y, acc[i2][j2]);
                    acc[i2][j2] = fmaf(a4[i2].z, b4[j2].z, acc[i2][j2]);
                    acc[i2][j2] = fmaf(a4[i2].w, b4[j2].w, acc[i2][j2]);
                }
            }
        }
        __syncthreads();
    }
    #pragma unroll
    for (int j2 = 0; j2 < 4; ++j2) {
        const int n = n0 + tn + 16 * j2;
        const float bv = bias[n];
        #pragma unroll
        for (int i2 = 0; i2 < 4; ++i2) {
            const int m = m0 + tm * 4 + i2;
            storeC(C + (size_t)m * N + n, acc[i2][j2] + bv);
        }
    }
}

// ---------------------------------------------------------------------------
// Kernel 5: recurrence. 64 WGs (1/batch) x 512 threads (8 waves).
// Wave q owns k-slice [q*32, q*32+32); lane l owns rows 4l..4l+3.
// W fragment in registers as f16x2 (v_dot2_f32_f16, f32 accum, 64 VGPRs).
// Per step:
//  phase1: 4 uniform ds_read_b128 of the h k-slice (broadcast, free dup)
//          -> 64 dot2/thread -> ONE ds_write_b128 of 4 partials to ps[q][4l..]
//  barrier
//  phase2 (tid<128): j-pair (2t,2t+1): 8x ds_read_b64 over ps[0..8)[2t..2t+2)
//          (2-way bank alias = free), + xp, tanh x2, packed f16x2 -> hbuf
//          double-buffer + coalesced global store.
//  barrier
// NO LDS atomics (R1's 8.6x regression: same-address ds atomics serialize
// across all 16 waves). xp prefetched one step ahead.
// ---------------------------------------------------------------------------
__global__ __launch_bounds__(512, 2) void recur_kernel(
    const float* __restrict__ Wm,              // [256][256] f32 row-major
    const __half* __restrict__ xp,             // [B][T][256] f16
    __half* __restrict__ hall)                 // [B][T][256] f16
{
    const int b = blockIdx.x;
    const int tid = threadIdx.x;
    const int l = tid & 63;
    const int q = tid >> 6;        // wave 0..7

    __shared__ float ps[8][HH];                // partial sums, 8 KB
    __shared__ unsigned int hbits[2][HH / 2];  // h as packed f16x2, 1 KB

    // W fragment: rows 4l..4l+3, cols q*32..q*32+32, converted to f16 pairs.
    f16x2 w2[4][16];
    #pragma unroll
    for (int r = 0; r < 4; ++r) {
        const float* Wp = Wm + (size_t)(4 * l + r) * HH + q * 32;
        #pragma unroll
        for (int c4 = 0; c4 < 8; ++c4) {
            float4 f = *(const float4*)(Wp + c4 * 4);
            w2[r][c4 * 2 + 0] = f16x2{(_Float16)f.x, (_Float16)f.y};
            w2[r][c4 * 2 + 1] = f16x2{(_Float16)f.z, (_Float16)f.w};
        }
    }
    if (tid < HH / 2) hbits[0][tid] = 0u;
    __syncthreads();

    const unsigned int* xpw = (const unsigned int*)(xp + (size_t)b * TT * HH);
    unsigned int* hw = (unsigned int*)(hall + (size_t)b * TT * HH);
    unsigned int xpc = (tid < 128) ? xpw[tid] : 0u;

    for (int t = 0; t < TT; ++t) {
        const int p = t & 1;
        // wave-uniform broadcast read of this wave's 32-element f16 h slice
        uint4 ha = *(const uint4*)&hbits[p][q * 16 + 0];
        uint4 hc = *(const uint4*)&hbits[p][q * 16 + 4];
        uint4 hd = *(const uint4*)&hbits[p][q * 16 + 8];
        uint4 he = *(const uint4*)&hbits[p][q * 16 + 12];
        f16x2 hv[16] = {
            __builtin_bit_cast(f16x2, ha.x), __builtin_bit_cast(f16x2, ha.y),
            __builtin_bit_cast(f16x2, ha.z), __builtin_bit_cast(f16x2, ha.w),
            __builtin_bit_cast(f16x2, hc.x), __builtin_bit_cast(f16x2, hc.y),
            __builtin_bit_cast(f16x2, hc.z), __builtin_bit_cast(f16x2, hc.w),
            __builtin_bit_cast(f16x2, hd.x), __builtin_bit_cast(f16x2, hd.y),
            __builtin_bit_cast(f16x2, hd.z), __builtin_bit_cast(f16x2, hd.w),
            __builtin_bit_cast(f16x2, he.x), __builtin_bit_cast(f16x2, he.y),
            __builtin_bit_cast(f16x2, he.z), __builtin_bit_cast(f16x2, he.w)};
        float a0 = 0.f, a1 = 0.f, a2 = 0.f, a3 = 0.f;
        #pragma unroll
        for (int c = 0; c < 16; ++c) {
            a0 = fdot2(w2[0][c], hv[c], a0);
            a1 = fdot2(w2[1][c], hv[c], a1);
            a2 = fdot2(w2[2][c], hv[c], a2);
            a3 = fdot2(w2[3][c], hv[c], a3);
        }
        *(float4*)(&ps[q][4 * l]) = make_float4(a0, a1, a2, a3);

        unsigned int xpn = 0u;
        if (tid < 128 && t + 1 < TT) xpn = xpw[(size_t)(t + 1) * 128 + tid];
        __syncthreads();

        if (tid < 128) {
            float sx = 0.f, sy = 0.f;
            #pragma unroll
            for (int qq = 0; qq < 8; ++qq) {
                float2 v = *(const float2*)&ps[qq][2 * tid];
                sx += v.x; sy += v.y;
            }
            f16x2 xv = __builtin_bit_cast(f16x2, xpc);
            float h0 = tanh_fast(sx + (float)xv.x);
            float h1 = tanh_fast(sy + (float)xv.y);
            unsigned int hb2 = __builtin_bit_cast(unsigned int,
                                                  f16x2{(_Float16)h0, (_Float16)h1});
            hbits[p ^ 1][tid] = hb2;
            hw[(size_t)t * 128 + tid] = hb2;
            xpc = xpn;
        }
        __syncthreads();
    }
}

// ---------------------------------------------------------------------------
extern "C" void kernel_launch(void* const* d_in, const int* in_sizes, int n_in,
                              void* d_out, int out_size, void* d_ws, size_t ws_size,
                              hipStream_t stream) {
    const float* x     = (const float*)d_in[0];   // [B][T][I]
    const float* W_in  = (const float*)d_in[1];   // [H][I]
    const float* b_in  = (const float*)d_in[2];   // [H]
    const float* W_out = (const float*)d_in[3];   // [O][H]
    const float* b_out = (const float*)d_in[4];   // [O]
    const float* u_raw = (const float*)d_in[5];   // [M][H]
    const float* sig   = (const float*)d_in[6];   // [H]
    const float* v_raw = (const float*)d_in[7];   // [M][H]
    float* out = (float*)d_out;                   // [B][T][O]

    char* ws = (char*)d_ws;
    size_t off = 0;
    auto alloc = [&](size_t bytes) -> void* {
        void* p = (void*)(ws + off);
        off += (bytes + 255) & ~((size_t)255);
        return p;
    };
    float* u_eff  = (float*)alloc((size_t)HH * HH * 4);
    float* v_eff  = (float*)alloc((size_t)HH * HH * 4);
    float* beta_u = (float*)alloc((size_t)HH * 4);
    float* beta_v = (float*)alloc((size_t)HH * 4);
    float* Ucol   = (float*)alloc((size_t)HH * HH * 4);
    float* Vrow   = (float*)alloc((size_t)HH * HH * 4);
    float* Wm     = (float*)alloc((size_t)HH * HH * 4);
    __half* xpbuf = (__half*)alloc((size_t)BB * TT * HH * 2);
    __half* hall  = (__half*)alloc((size_t)BB * TT * HH * 2);
    (void)ws_size; (void)in_sizes; (void)n_in; (void)out_size;

    prep_kernel<<<2 * HH, 64, 0, stream>>>(u_raw, v_raw, u_eff, v_eff, beta_u, beta_v);
    hh_kernel<<<(2 * HH) / 4, 256, 0, stream>>>(u_eff, v_eff, beta_u, beta_v, Ucol, Vrow);
    w_kernel<<<HH, HH, 0, stream>>>(Ucol, Vrow, sig, Wm);
    gemm_bias<float, __half>
        <<<dim3((BB * TT) / 64, HH / 64), 256, 0, stream>>>(x, W_in, b_in, xpbuf, BB * TT, HH, II);
    recur_kernel<<<BB, 512, 0, stream>>>(Wm, xpbuf, hall);
    gemm_bias<__half, float>
        <<<dim3((BB * TT) / 64, OO / 64), 256, 0, stream>>>(hall, W_out, b_out, out, BB * TT, OO, HH);
}

// Round 4
// 1546.735 us; speedup vs baseline: 7.5757x; 1.1175x over previous
//
#include <hip/hip_runtime.h>
#include <hip/hip_bf16.h>
#include <hip/hip_fp16.h>

// SVD-RNN: W = U diag(s) V from Householder chains; h_t = tanh(xp_t + W h_{t-1});
// out_t = h_t W_out^T + b_out.
#define BB 64
#define TT 2048
#define II 128
#define HH 256
#define OO 128
#define RCH 8                      // recurrence chunk length (global I/O batching)

typedef _Float16 f16x2 __attribute__((ext_vector_type(2)));

#if __has_builtin(__builtin_amdgcn_fdot2)
__device__ __forceinline__ float fdot2(f16x2 a, f16x2 b, float c) {
    return __builtin_amdgcn_fdot2(a, b, c, false);
}
#else
__device__ __forceinline__ float fdot2(f16x2 a, f16x2 b, float c) {
    return fmaf((float)a.x, (float)b.x, fmaf((float)a.y, (float)b.y, c));
}
#endif

__device__ __forceinline__ f16x2 u2h(unsigned int u) { return __builtin_bit_cast(f16x2, u); }
__device__ __forceinline__ unsigned int packf16(float a, float b) {
    return __builtin_bit_cast(unsigned int, f16x2{(_Float16)a, (_Float16)b});
}

__device__ __forceinline__ float tanh_fast(float x) {
    float xc = fminf(fmaxf(x, -9.0f), 9.0f);
    float e = __expf(2.0f * xc);
    return (e - 1.0f) * __fdividef(1.0f, e + 1.0f);
}

// ---------------------------------------------------------------------------
// Kernel 1: masked+flipped Householder vectors and betas.
// ---------------------------------------------------------------------------
__global__ __launch_bounds__(64) void prep_kernel(
    const float* __restrict__ u_raw, const float* __restrict__ v_raw,
    float* __restrict__ u_eff, float* __restrict__ v_eff,
    float* __restrict__ beta_u, float* __restrict__ beta_v)
{
    const int row = blockIdx.x;
    const int lane = threadIdx.x;
    const bool isU = row < HH;
    const int i = isU ? row : row - HH;
    const float* src = isU ? (u_raw + (size_t)i * HH) : (v_raw + (size_t)(HH - 1 - i) * HH);
    float* dst = (isU ? u_eff : v_eff) + (size_t)i * HH;
    const int lo = isU ? (HH - 1 - i) : i;
    float ss = 0.0f;
    for (int c = lane; c < HH; c += 64) {
        float vv = (c >= lo) ? src[HH - 1 - c] : 0.0f;
        dst[c] = vv;
        ss += vv * vv;
    }
    for (int m = 1; m < 64; m <<= 1) ss += __shfl_xor(ss, m, 64);
    if (lane == 0) (isU ? beta_u : beta_v)[i] = 2.0f / ss;
}

// ---------------------------------------------------------------------------
// Kernel 2: Householder chain per column.
// ---------------------------------------------------------------------------
__global__ __launch_bounds__(256) void hh_kernel(
    const float* __restrict__ u_eff, const float* __restrict__ v_eff,
    const float* __restrict__ beta_u, const float* __restrict__ beta_v,
    float* __restrict__ Ucol, float* __restrict__ Vrow)
{
    const int wid = blockIdx.x * 4 + (threadIdx.x >> 6);
    const int lane = threadIdx.x & 63;
    const bool isU = wid < HH;
    const int j = isU ? wid : wid - HH;
    const float* eff = isU ? u_eff : v_eff;
    const float* beta = isU ? beta_u : beta_v;

    float cr0 = (j == 4 * lane + 0) ? 1.0f : 0.0f;
    float cr1 = (j == 4 * lane + 1) ? 1.0f : 0.0f;
    float cr2 = (j == 4 * lane + 2) ? 1.0f : 0.0f;
    float cr3 = (j == 4 * lane + 3) ? 1.0f : 0.0f;

    const int i0 = isU ? (HH - 1 - j) : 0;
    for (int i = i0; i < HH; ++i) {
        const float4 v4 = *(const float4*)(eff + (size_t)i * HH + lane * 4);
        float d = v4.x * cr0 + v4.y * cr1 + v4.z * cr2 + v4.w * cr3;
        for (int m = 1; m < 64; m <<= 1) d += __shfl_xor(d, m, 64);
        const float t = beta[i] * d;
        cr0 = fmaf(-t, v4.x, cr0);
        cr1 = fmaf(-t, v4.y, cr1);
        cr2 = fmaf(-t, v4.z, cr2);
        cr3 = fmaf(-t, v4.w, cr3);
    }
    if (isU) {
        *(float4*)(Ucol + (size_t)j * HH + lane * 4) = make_float4(cr0, cr1, cr2, cr3);
    } else {
        Vrow[(size_t)(4 * lane + 0) * HH + j] = cr0;
        Vrow[(size_t)(4 * lane + 1) * HH + j] = cr1;
        Vrow[(size_t)(4 * lane + 2) * HH + j] = cr2;
        Vrow[(size_t)(4 * lane + 3) * HH + j] = cr3;
    }
}

// ---------------------------------------------------------------------------
// Kernel 3: W[r][c] = sum_k Ucol[k][r] * sig[k] * Vrow[k][c]
// ---------------------------------------------------------------------------
__global__ __launch_bounds__(256) void w_kernel(
    const float* __restrict__ Ucol, const float* __restrict__ Vrow,
    const float* __restrict__ sig, float* __restrict__ Wm)
{
    const int r = blockIdx.x;
    const int c = threadIdx.x;
    float acc = 0.0f;
    #pragma unroll 4
    for (int k = 0; k < HH; ++k) {
        acc = fmaf(Ucol[(size_t)k * HH + r] * sig[k], Vrow[(size_t)k * HH + c], acc);
    }
    Wm[(size_t)r * HH + c] = acc;
}

// ---------------------------------------------------------------------------
// Tiled GEMM with bias, f16x2/dot2 inner: C[M][N] = A[M][K]*B[N][K]^T + bias.
// Tiles staged in LDS as packed f16x2 (halves LDS bytes+instr vs fp32).
// BM=BN=64, BK=32, 256 threads, 4x4 micro-tile.
// ---------------------------------------------------------------------------
__device__ __forceinline__ uint4 stage8(const float* p) {
    float4 a = *(const float4*)p;
    float4 b = *(const float4*)(p + 4);
    return make_uint4(packf16(a.x, a.y), packf16(a.z, a.w),
                      packf16(b.x, b.y), packf16(b.z, b.w));
}
__device__ __forceinline__ uint4 stage8(const __half* p) {
    return *(const uint4*)p;
}
__device__ __forceinline__ void storeC(float* p, float v) { *p = v; }
__device__ __forceinline__ void storeC(__half* p, float v) { *p = __float2half_rn(v); }

template <typename AT, typename OT>
__global__ __launch_bounds__(256) void gemm_bias(
    const AT* __restrict__ A, const float* __restrict__ Bm,
    const float* __restrict__ bias, OT* __restrict__ C,
    int M, int N, int K)
{
    __shared__ unsigned int As[64][20];   // 16 uints used (32 k as f16x2), pad->20
    __shared__ unsigned int Bs[64][20];
    const int m0 = blockIdx.x * 64;
    const int n0 = blockIdx.y * 64;
    const int tid = threadIdx.x;
    const int lr = tid >> 2;              // staging row 0..63
    const int lc = (tid & 3) << 3;        // staging elem offset 0,8,16,24
    const int tm = tid >> 4;              // 0..15
    const int tn = tid & 15;              // 0..15
    float acc[4][4] = {};
    for (int k0 = 0; k0 < K; k0 += 32) {
        *(uint4*)&As[lr][lc >> 1] = stage8(A + (size_t)(m0 + lr) * K + k0 + lc);
        *(uint4*)&Bs[lr][lc >> 1] = stage8(Bm + (size_t)(n0 + lr) * K + k0 + lc);
        __syncthreads();
        #pragma unroll
        for (int k8 = 0; k8 < 4; ++k8) {  // 8 k-values per iter
            uint4 a4[4], b4[4];
            #pragma unroll
            for (int r = 0; r < 4; ++r) {
                a4[r] = *(const uint4*)&As[tm * 4 + r][k8 * 4];
                b4[r] = *(const uint4*)&Bs[tn + 16 * r][k8 * 4];
            }
            #pragma unroll
            for (int i2 = 0; i2 < 4; ++i2) {
                #pragma unroll
                for (int j2 = 0; j2 < 4; ++j2) {
                    acc[i2][j2] = fdot2(u2h(a4[i2].x), u2h(b4[j2].x), acc[i2][j2]);
                    acc[i2][j2] = fdot2(u2h(a4[i2].y), u2h(b4[j2].y), acc[i2][j2]);
                    acc[i2][j2] = fdot2(u2h(a4[i2].z), u2h(b4[j2].z), acc[i2][j2]);
                    acc[i2][j2] = fdot2(u2h(a4[i2].w), u2h(b4[j2].w), acc[i2][j2]);
                }
            }
        }
        __syncthreads();
    }
    #pragma unroll
    for (int j2 = 0; j2 < 4; ++j2) {
        const int n = n0 + tn + 16 * j2;
        const float bv = bias[n];
        #pragma unroll
        for (int i2 = 0; i2 < 4; ++i2) {
            const int m = m0 + tm * 4 + i2;
            storeC(C + (size_t)m * N + n, acc[i2][j2] + bv);
        }
    }
}

// ---------------------------------------------------------------------------
// Kernel 5: recurrence. 64 WGs (1/batch) x 512 threads (8 waves).
// Wave q owns k-slice [q*32,q*32+32); lane l owns rows 4l..4l+3. W fragment in
// registers as f16x2 (v_dot2_f32_f16). Per step: phase1 (4 uniform b128 h
// reads + 64 dot2 + 1 b128 ps write), barrier, phase2 (tid<128: 8 b64 ps
// reads + xp + 2x tanh + hbuf write), barrier.
// R3 FIX: global I/O is CHUNKED (RCH=8 steps) — per-step global stores/loads
// at barriers forced vmcnt(0) drains (~800 cyc/step exposed latency in
// R0/R2). xp for the next chunk is loaded into registers once per chunk at
// the start of phase1 step 0 (max work before the draining barrier); h
// outputs are buffered in registers and stored once per chunk end.
// NO LDS atomics (R1: same-address ds atomics serialize, 8.6x regression).
// ---------------------------------------------------------------------------
__global__ __launch_bounds__(512) void recur_kernel(
    const float* __restrict__ Wm,              // [256][256] f32 row-major
    const __half* __restrict__ xp,             // [B][T][256] f16
    __half* __restrict__ hall)                 // [B][T][256] f16
{
    const int b = blockIdx.x;
    const int tid = threadIdx.x;
    const int l = tid & 63;
    const int q = tid >> 6;        // wave 0..7

    __shared__ float ps[8][HH];                // partial sums, 8 KB
    __shared__ unsigned int hbits[2][HH / 2];  // h as packed f16x2, 1 KB

    // W fragment: rows 4l..4l+3, cols q*32..q*32+32, as f16 pairs (64 VGPRs).
    f16x2 w2[4][16];
    #pragma unroll
    for (int r = 0; r < 4; ++r) {
        const float* Wp = Wm + (size_t)(4 * l + r) * HH + q * 32;
        #pragma unroll
        for (int c4 = 0; c4 < 8; ++c4) {
            float4 f = *(const float4*)(Wp + c4 * 4);
            w2[r][c4 * 2 + 0] = f16x2{(_Float16)f.x, (_Float16)f.y};
            w2[r][c4 * 2 + 1] = f16x2{(_Float16)f.z, (_Float16)f.w};
        }
    }
    if (tid < HH / 2) hbits[0][tid] = 0u;
    __syncthreads();

    const unsigned int* xpw = (const unsigned int*)(xp + (size_t)b * TT * HH);
    unsigned int* hw = (unsigned int*)(hall + (size_t)b * TT * HH);

    unsigned int xpcur[RCH], xpnxt[RCH], hst[RCH];
    if (tid < 128) {
        #pragma unroll
        for (int s = 0; s < RCH; ++s) xpcur[s] = xpw[(size_t)s * 128 + tid];
    }

    const int nch = TT / RCH;
    for (int c = 0; c < nch; ++c) {
        #pragma unroll
        for (int s = 0; s < RCH; ++s) {
            const int p = s & 1;
            // issue next chunk's xp loads at the top of step 0 (waves 0-1
            // only): ~500 cyc of phase1 work before the draining barrier.
            if (s == 0 && tid < 128 && c + 1 < nch) {
                const unsigned int* xn = xpw + (size_t)(c + 1) * RCH * 128 + tid;
                #pragma unroll
                for (int s2 = 0; s2 < RCH; ++s2) xpnxt[s2] = xn[(size_t)s2 * 128];
            }
            // wave-uniform broadcast read of this wave's 32-k f16 h slice
            uint4 ha = *(const uint4*)&hbits[p][q * 16 + 0];
            uint4 hc = *(const uint4*)&hbits[p][q * 16 + 4];
            uint4 hd = *(const uint4*)&hbits[p][q * 16 + 8];
            uint4 he = *(const uint4*)&hbits[p][q * 16 + 12];
            f16x2 hv[16] = {
                u2h(ha.x), u2h(ha.y), u2h(ha.z), u2h(ha.w),
                u2h(hc.x), u2h(hc.y), u2h(hc.z), u2h(hc.w),
                u2h(hd.x), u2h(hd.y), u2h(hd.z), u2h(hd.w),
                u2h(he.x), u2h(he.y), u2h(he.z), u2h(he.w)};
            float a0 = 0.f, a1 = 0.f, a2 = 0.f, a3 = 0.f;
            #pragma unroll
            for (int cc = 0; cc < 16; ++cc) {
                a0 = fdot2(w2[0][cc], hv[cc], a0);
                a1 = fdot2(w2[1][cc], hv[cc], a1);
                a2 = fdot2(w2[2][cc], hv[cc], a2);
                a3 = fdot2(w2[3][cc], hv[cc], a3);
            }
            *(float4*)(&ps[q][4 * l]) = make_float4(a0, a1, a2, a3);
            __syncthreads();

            if (tid < 128) {
                float sx = 0.f, sy = 0.f;
                #pragma unroll
                for (int qq = 0; qq < 8; ++qq) {
                    float2 v = *(const float2*)&ps[qq][2 * tid];
                    sx += v.x; sy += v.y;
                }
                f16x2 xv = u2h(xpcur[s]);
                float h0 = tanh_fast(sx + (float)xv.x);
                float h1 = tanh_fast(sy + (float)xv.y);
                unsigned int hb2 = packf16(h0, h1);
                hbits[p ^ 1][tid] = hb2;
                hst[s] = hb2;
            }
            __syncthreads();
        }
        // chunk epilogue: store 8 h steps, rotate xp buffers (waves 0-1 only)
        if (tid < 128) {
            unsigned int* hwc = hw + (size_t)c * RCH * 128 + tid;
            #pragma unroll
            for (int s = 0; s < RCH; ++s) hwc[(size_t)s * 128] = hst[s];
            #pragma unroll
            for (int s = 0; s < RCH; ++s) xpcur[s] = xpnxt[s];
        }
    }
}

// ---------------------------------------------------------------------------
extern "C" void kernel_launch(void* const* d_in, const int* in_sizes, int n_in,
                              void* d_out, int out_size, void* d_ws, size_t ws_size,
                              hipStream_t stream) {
    const float* x     = (const float*)d_in[0];   // [B][T][I]
    const float* W_in  = (const float*)d_in[1];   // [H][I]
    const float* b_in  = (const float*)d_in[2];   // [H]
    const float* W_out = (const float*)d_in[3];   // [O][H]
    const float* b_out = (const float*)d_in[4];   // [O]
    const float* u_raw = (const float*)d_in[5];   // [M][H]
    const float* sig   = (const float*)d_in[6];   // [H]
    const float* v_raw = (const float*)d_in[7];   // [M][H]
    float* out = (float*)d_out;                   // [B][T][O]

    char* ws = (char*)d_ws;
    size_t off = 0;
    auto alloc = [&](size_t bytes) -> void* {
        void* p = (void*)(ws + off);
        off += (bytes + 255) & ~((size_t)255);
        return p;
    };
    float* u_eff  = (float*)alloc((size_t)HH * HH * 4);
    float* v_eff  = (float*)alloc((size_t)HH * HH * 4);
    float* beta_u = (float*)alloc((size_t)HH * 4);
    float* beta_v = (float*)alloc((size_t)HH * 4);
    float* Ucol   = (float*)alloc((size_t)HH * HH * 4);
    float* Vrow   = (float*)alloc((size_t)HH * HH * 4);
    float* Wm     = (float*)alloc((size_t)HH * HH * 4);
    __half* xpbuf = (__half*)alloc((size_t)BB * TT * HH * 2);
    __half* hall  = (__half*)alloc((size_t)BB * TT * HH * 2);
    (void)ws_size; (void)in_sizes; (void)n_in; (void)out_size;

    prep_kernel<<<2 * HH, 64, 0, stream>>>(u_raw, v_raw, u_eff, v_eff, beta_u, beta_v);
    hh_kernel<<<(2 * HH) / 4, 256, 0, stream>>>(u_eff, v_eff, beta_u, beta_v, Ucol, Vrow);
    w_kernel<<<HH, HH, 0, stream>>>(Ucol, Vrow, sig, Wm);
    gemm_bias<float, __half>
        <<<dim3((BB * TT) / 64, HH / 64), 256, 0, stream>>>(x, W_in, b_in, xpbuf, BB * TT, HH, II);
    recur_kernel<<<BB, 512, 0, stream>>>(Wm, xpbuf, hall);
    gemm_bias<__half, float>
        <<<dim3((BB * TT) / 64, OO / 64), 256, 0, stream>>>(hall, W_out, b_out, out, BB * TT, OO, HH);
}